// Round 12
// baseline (132.801 us; speedup 1.0000x reference)
//
#include <hip/hip_runtime.h>
#include <math.h>
#include <stdint.h>

#define D 64
#define WSZ 128      // dsts per window
#define WSHIFT 7
#define QCAP 4096    // max edges/window (mean 2048, ~17 sigma headroom)
#define EPT 16       // edges per thread in bin role
#define NWMAX 512    // supports Ndst <= 65536

typedef __attribute__((ext_vector_type(8))) short bf16x8;
typedef __attribute__((ext_vector_type(4))) float f32x4;

__device__ inline ushort bf16_rne_u(float v) {
    uint32_t u = __float_as_uint(v);
    return (ushort)((u + 0x7FFFu + ((u >> 16) & 1u)) >> 16);
}

// ================= fused prep =================
// blocks [0, packBlocks): pack  f = relu(h @ W^T + b)
//   R12: packed is QUARTER-SLICED: packed[(q*Nsrc + row)*16 + (col&15)], q=col>>4.
//   Each 3.2MB slice fits one XCD's 4MiB L2 -> main's gathers become L2-local.
// blocks [packBlocks, ..): BIN role — read edges once, LDS-count per 128-dst
//   window, ~77K global atomics total (R11: this took scatter off the critical path).
__global__ __launch_bounds__(256) void prep_kernel(const float* __restrict__ h,
                                                   const float* __restrict__ W,
                                                   const float* __restrict__ b,
                                                   const int* __restrict__ src_idx,
                                                   const int* __restrict__ dst_idx,
                                                   uint32_t* __restrict__ packed,
                                                   int* __restrict__ qcnt,
                                                   uint32_t* __restrict__ queue,
                                                   int Nsrc, int Ndst, int E, int packBlocks) {
    __shared__ ushort hT[64 * 64];   // pack: bf16 x-tile (8 KB)
    __shared__ ushort wT[64 * 64];   // pack: bf16 W (8 KB)
    __shared__ float bs[64];
    __shared__ int wcount[NWMAX];    // bin: per-window count (2 KB)
    __shared__ int wbase[NWMAX];     // bin: per-window cursor (2 KB)

    if ((int)blockIdx.x < packBlocks) {
        const int t = threadIdx.x;
        const int R0 = blockIdx.x * 64;

        if (t < 64) bs[t] = b[t];
#pragma unroll
        for (int k = 0; k < 4; ++k) {
            int f4 = k * 256 + t;
            int row = f4 >> 4;
            int c4 = (f4 & 15) * 4;
            int grow = min(R0 + row, Nsrc - 1);
            float4 v = reinterpret_cast<const float4*>(h)[(size_t)grow * 16 + (f4 & 15)];
            hT[row * 64 + c4 + 0] = bf16_rne_u(v.x);
            hT[row * 64 + c4 + 1] = bf16_rne_u(v.y);
            hT[row * 64 + c4 + 2] = bf16_rne_u(v.z);
            hT[row * 64 + c4 + 3] = bf16_rne_u(v.w);
            float4 w = reinterpret_cast<const float4*>(W)[f4];
            wT[row * 64 + c4 + 0] = bf16_rne_u(w.x);
            wT[row * 64 + c4 + 1] = bf16_rne_u(w.y);
            wT[row * 64 + c4 + 2] = bf16_rne_u(w.z);
            wT[row * 64 + c4 + 3] = bf16_rne_u(w.w);
        }
        __syncthreads();

        // MFMA 16x16x32 bf16; A[m=lane&15][k=quad*8+j]; C/D col=lane&15,row=quad*4+reg
        const int wave = t >> 6;
        const int lane = t & 63;
        const int m = lane & 15;
        const int quad = lane >> 4;

        bf16x8 afrag[2];
#pragma unroll
        for (int ks = 0; ks < 2; ++ks)
            afrag[ks] = *reinterpret_cast<const bf16x8*>(&hT[(wave * 16 + m) * 64 + ks * 32 + quad * 8]);

#pragma unroll
        for (int nt = 0; nt < 4; ++nt) {
            const int c0 = nt * 16;
            f32x4 acc = {0.f, 0.f, 0.f, 0.f};
#pragma unroll
            for (int ks = 0; ks < 2; ++ks) {
                bf16x8 bfrag = *reinterpret_cast<const bf16x8*>(&wT[(c0 + m) * 64 + ks * 32 + quad * 8]);
                acc = __builtin_amdgcn_mfma_f32_16x16x32_bf16(afrag[ks], bfrag, acc, 0, 0, 0);
            }
            const int col = c0 + m;
            const float bias = bs[col];
#pragma unroll
            for (int reg = 0; reg < 4; ++reg) {
                const int tr = wave * 16 + quad * 4 + reg;
                const int row = R0 + tr;
                if (row < Nsrc) {
                    float f = fmaxf(acc[reg] + bias, 0.f);
                    uint32_t val = (uint32_t)hT[tr * 64 + col] | ((uint32_t)bf16_rne_u(f) << 16);
                    // quarter-sliced layout
                    __builtin_nontemporal_store(val,
                        &packed[((size_t)nt * Nsrc + row) * 16 + m]);
                }
            }
        }
    } else {
        // ---- BIN role ----
        const int bid = (int)blockIdx.x - packBlocks;
        const int t = threadIdx.x;
        for (int k = t; k < NWMAX; k += 256) wcount[k] = 0;
        __syncthreads();

        const int i = bid * 256 + t;
        const int e0 = i * EPT;
        const bool full = (e0 + EPT <= E);

        int4 d0, d1, d2, d3, s0, s1, s2, s3;
        if (full) {
            const int4* dp = reinterpret_cast<const int4*>(dst_idx) + i * 4;
            const int4* sp = reinterpret_cast<const int4*>(src_idx) + i * 4;
            d0 = dp[0]; d1 = dp[1]; d2 = dp[2]; d3 = dp[3];
            s0 = sp[0]; s1 = sp[1]; s2 = sp[2]; s3 = sp[3];
            atomicAdd(&wcount[d0.x >> WSHIFT], 1); atomicAdd(&wcount[d0.y >> WSHIFT], 1);
            atomicAdd(&wcount[d0.z >> WSHIFT], 1); atomicAdd(&wcount[d0.w >> WSHIFT], 1);
            atomicAdd(&wcount[d1.x >> WSHIFT], 1); atomicAdd(&wcount[d1.y >> WSHIFT], 1);
            atomicAdd(&wcount[d1.z >> WSHIFT], 1); atomicAdd(&wcount[d1.w >> WSHIFT], 1);
            atomicAdd(&wcount[d2.x >> WSHIFT], 1); atomicAdd(&wcount[d2.y >> WSHIFT], 1);
            atomicAdd(&wcount[d2.z >> WSHIFT], 1); atomicAdd(&wcount[d2.w >> WSHIFT], 1);
            atomicAdd(&wcount[d3.x >> WSHIFT], 1); atomicAdd(&wcount[d3.y >> WSHIFT], 1);
            atomicAdd(&wcount[d3.z >> WSHIFT], 1); atomicAdd(&wcount[d3.w >> WSHIFT], 1);
        } else {
            for (int e = e0; e < E; ++e) atomicAdd(&wcount[dst_idx[e] >> WSHIFT], 1);
        }
        __syncthreads();

        for (int k = t; k < NWMAX; k += 256) {
            int c = wcount[k];
            wbase[k] = (c > 0) ? atomicAdd(&qcnt[k], c) : 0;
        }
        __syncthreads();

#define EMIT(dv, sv)                                                            \
        {                                                                       \
            int w_ = (dv) >> WSHIFT;                                            \
            int pos_ = atomicAdd(&wbase[w_], 1);                                \
            if (pos_ < QCAP)                                                    \
                queue[(size_t)w_ * QCAP + pos_] =                               \
                    (uint32_t)(sv) | ((uint32_t)((dv) & (WSZ - 1)) << 16);      \
        }
        if (full) {
            EMIT(d0.x, s0.x) EMIT(d0.y, s0.y) EMIT(d0.z, s0.z) EMIT(d0.w, s0.w)
            EMIT(d1.x, s1.x) EMIT(d1.y, s1.y) EMIT(d1.z, s1.z) EMIT(d1.w, s1.w)
            EMIT(d2.x, s2.x) EMIT(d2.y, s2.y) EMIT(d2.z, s2.z) EMIT(d2.w, s2.w)
            EMIT(d3.x, s3.x) EMIT(d3.y, s3.y) EMIT(d3.z, s3.z) EMIT(d3.w, s3.w)
        } else {
            for (int e = e0; e < E; ++e) { EMIT(dst_idx[e], src_idx[e]) }
        }
#undef EMIT
    }
}

// ================= phase B: per-window LDS counting sort -> CSR =================
__global__ __launch_bounds__(256) void sortwin_kernel(const uint32_t* __restrict__ queue,
                                                      const int* __restrict__ qcnt,
                                                      uint32_t* __restrict__ csr,
                                                      int* __restrict__ cnt,
                                                      int* __restrict__ row_start, int Ndst) {
    __shared__ uint32_t ent[QCAP];   // 16 KB
    __shared__ uint32_t srt[QCAP];   // 16 KB
    __shared__ int hist[WSZ], sc[WSZ], cur[WSZ];
    const int w = blockIdx.x;
    const int t = threadIdx.x;
    const int n = min(qcnt[w], QCAP);

    for (int k = t; k < n; k += 256) ent[k] = queue[(size_t)w * QCAP + k];
    if (t < WSZ) hist[t] = 0;
    __syncthreads();
    for (int k = t; k < n; k += 256) atomicAdd(&hist[(ent[k] >> 16) & (WSZ - 1)], 1);
    __syncthreads();
    if (t < WSZ) sc[t] = hist[t];
    __syncthreads();
    for (int off = 1; off < WSZ; off <<= 1) {      // Hillis-Steele inclusive scan
        int v = (t >= off && t < WSZ) ? sc[t - off] : 0;
        __syncthreads();
        if (t < WSZ) sc[t] += v;
        __syncthreads();
    }
    if (t < WSZ) cur[t] = sc[t] - hist[t];         // exclusive
    __syncthreads();
    for (int k = t; k < n; k += 256) {
        uint32_t e = ent[k];
        int dl = (e >> 16) & (WSZ - 1);
        int pos = atomicAdd(&cur[dl], 1);          // LDS atomic
        srt[pos] = e & 0xFFFFu;                    // src index
    }
    __syncthreads();
    const size_t obase = (size_t)w * QCAP;
    for (int k = t; k < n; k += 256) csr[obase + k] = srt[k];
    if (t < WSZ) {
        int j = w * WSZ + t;
        if (j < Ndst) {
            cnt[j] = hist[t];
            row_start[j] = (int)obase + (sc[t] - hist[t]);
        }
    }
}

// ---------------- per-dim accumulate: l += exp(x*y); a += exp(x*y)*f ----------------
__device__ inline void stepd(uint32_t u, float y, float& l, float& a) {
    float x = __uint_as_float(u << 16);           // low bf16 -> f32
    float f = __uint_as_float(u & 0xFFFF0000u);   // high bf16 -> f32
    float pe = __expf(x * y);                     // no max-sub: |x*y| <~ 30, safe in f32
    l += pe;
    a += pe * f;
}

__device__ inline void step4(uint4 u, const float4& y, float4& l, float4& a) {
    stepd(u.x, y.x, l.x, a.x);
    stepd(u.y, y.y, l.y, a.y);
    stepd(u.z, y.z, l.z, a.z);
    stepd(u.w, y.w, l.w, a.w);
}

// ---------------- main: quarter-sliced. Block = (64 dsts) x (one 16-dim quarter).
// qtr = blockIdx%4: with blockIdx%8 XCD round-robin, each XCD touches ONE 3.2MB
// slice -> edge gathers hit the local L2. Per edge: 4 lanes x 16B = one 64B line.
__global__ __launch_bounds__(256) void gat_main_kernel(const uint32_t* __restrict__ packed,
                                                       const float* __restrict__ h_dst,
                                                       const int* __restrict__ cnt,
                                                       const int* __restrict__ row_start,
                                                       const uint32_t* __restrict__ csr,
                                                       float* __restrict__ out,
                                                       int Nsrc, int Ndst) {
    const int qtr = blockIdx.x & 3;
    const int g = threadIdx.x >> 2;   // dst group 0..63
    const int c = threadIdx.x & 3;    // float4 slot within 16-dim quarter
    const int j = (blockIdx.x >> 2) * 64 + g;
    if (j >= Ndst) return;

    const float4 y = reinterpret_cast<const float4*>(h_dst + (size_t)j * D + qtr * 16)[c];
    const int n = cnt[j];
    const uint32_t* sl = csr + row_start[j];
    const uint32_t* pq = packed + (size_t)qtr * Nsrc * 16;

    float4 l0 = make_float4(0.f, 0.f, 0.f, 0.f), a0 = l0;
    float4 l1 = l0, a1 = l0, l2 = l0, a2 = l0, l3 = l0, a3 = l0;

    int p = 0;
    for (; p + 3 < n; p += 4) {
        uint32_t s0 = sl[p], s1 = sl[p + 1], s2 = sl[p + 2], s3 = sl[p + 3];
        uint4 u0 = reinterpret_cast<const uint4*>(pq + (size_t)s0 * 16)[c];
        uint4 u1 = reinterpret_cast<const uint4*>(pq + (size_t)s1 * 16)[c];
        uint4 u2 = reinterpret_cast<const uint4*>(pq + (size_t)s2 * 16)[c];
        uint4 u3 = reinterpret_cast<const uint4*>(pq + (size_t)s3 * 16)[c];
        step4(u0, y, l0, a0);
        step4(u1, y, l1, a1);
        step4(u2, y, l2, a2);
        step4(u3, y, l3, a3);
    }
    for (; p < n; ++p) {
        uint32_t s0 = sl[p];
        uint4 u0 = reinterpret_cast<const uint4*>(pq + (size_t)s0 * 16)[c];
        step4(u0, y, l0, a0);
    }

    l0.x += l1.x + l2.x + l3.x; a0.x += a1.x + a2.x + a3.x;
    l0.y += l1.y + l2.y + l3.y; a0.y += a1.y + a2.y + a3.y;
    l0.z += l1.z + l2.z + l3.z; a0.z += a1.z + a2.z + a3.z;
    l0.w += l1.w + l2.w + l3.w; a0.w += a1.w + a2.w + a3.w;

    float4 o;
    o.x = (l0.x > 0.f) ? a0.x / l0.x : 0.f;   // empty segment -> 0 (matches ref)
    o.y = (l0.y > 0.f) ? a0.y / l0.y : 0.f;
    o.z = (l0.z > 0.f) ? a0.z / l0.z : 0.f;
    o.w = (l0.w > 0.f) ? a0.w / l0.w : 0.f;
    reinterpret_cast<float4*>(out + (size_t)j * D + qtr * 16)[c] = o;
}

extern "C" void kernel_launch(void* const* d_in, const int* in_sizes, int n_in,
                              void* d_out, int out_size, void* d_ws, size_t ws_size,
                              hipStream_t stream) {
    const float* h_src = (const float*)d_in[0];
    const float* h_dst = (const float*)d_in[1];
    const int* src_idx = (const int*)d_in[2];
    const int* dst_idx = (const int*)d_in[3];
    const float* W_src = (const float*)d_in[4];
    const float* b_src = (const float*)d_in[5];
    float* out = (float*)d_out;

    const int Nsrc = in_sizes[0] / D;
    const int Ndst = in_sizes[1] / D;
    const int E = in_sizes[2];
    const int NW = (Ndst + WSZ - 1) >> WSHIFT;

    const int packBlocks = (Nsrc + 63) / 64;
    const int binBlocks = (E + 256 * EPT - 1) / (256 * EPT);   // read-once

    // workspace layout
    uint32_t* packed   = (uint32_t*)d_ws;                       // Nsrc*D u32 (4 slices)
    int*      qcnt     = (int*)(packed + (size_t)Nsrc * D);     // NWMAX
    uint32_t* queue    = (uint32_t*)(qcnt + NWMAX);             // NW*QCAP
    uint32_t* csr      = queue + (size_t)NW * QCAP;             // NW*QCAP
    int*      cnt      = (int*)(csr + (size_t)NW * QCAP);       // Ndst
    int*      row_start= cnt + Ndst;                            // Ndst

    hipMemsetAsync(qcnt, 0, sizeof(int) * NWMAX, stream);

    prep_kernel<<<packBlocks + binBlocks, 256, 0, stream>>>(
        h_src, W_src, b_src, src_idx, dst_idx, packed, qcnt, queue,
        Nsrc, Ndst, E, packBlocks);
    sortwin_kernel<<<NW, 256, 0, stream>>>(queue, qcnt, csr, cnt, row_start, Ndst);
    const int mainBlocks = ((Ndst + 63) / 64) * 4;
    gat_main_kernel<<<mainBlocks, 256, 0, stream>>>(packed, h_dst, cnt, row_start,
                                                    csr, out, Nsrc, Ndst);
}

// Round 13
// 131.369 us; speedup vs baseline: 1.0109x; 1.0109x over previous
//
#include <hip/hip_runtime.h>
#include <math.h>
#include <stdint.h>

#define D 64
#define WSZ 64       // dsts per window
#define WSHIFT 6
#define QCAP 2048    // max edges/window (mean 1024, sigma~32 -> 32 sigma headroom)
#define EPT 16       // edges per thread in bin role
#define NWMAX 1024   // supports Ndst <= 65536

typedef __attribute__((ext_vector_type(8))) short bf16x8;
typedef __attribute__((ext_vector_type(4))) float f32x4;

__device__ inline ushort bf16_rne_u(float v) {
    uint32_t u = __float_as_uint(v);
    return (ushort)((u + 0x7FFFu + ((u >> 16) & 1u)) >> 16);
}

// ================= fused prep =================
// blocks [0, packBlocks): pack  f = relu(h @ W^T + b); packed[row*64+col] =
//   bf16(x) | bf16(f)<<16  (R11 row-major layout — R12 slicing was a null result).
// blocks [packBlocks, ..): BIN role — read edges once, LDS-count per 64-dst
//   window, ~150K global atomics total (R11: killing the 800K per-edge atomics
//   was the scatter fix), emit (src | dlocal<<16) into per-window queues.
__global__ __launch_bounds__(256) void prep_kernel(const float* __restrict__ h,
                                                   const float* __restrict__ W,
                                                   const float* __restrict__ b,
                                                   const int* __restrict__ src_idx,
                                                   const int* __restrict__ dst_idx,
                                                   uint32_t* __restrict__ packed,
                                                   int* __restrict__ qcnt,
                                                   uint32_t* __restrict__ queue,
                                                   int Nsrc, int Ndst, int E,
                                                   int packBlocks, int NW) {
    __shared__ ushort hT[64 * 64];   // pack: bf16 x-tile (8 KB)
    __shared__ ushort wT[64 * 64];   // pack: bf16 W (8 KB)
    __shared__ float bs[64];
    __shared__ int wcount[NWMAX];    // bin: per-window count (4 KB)
    __shared__ int wbase[NWMAX];     // bin: per-window cursor (4 KB)

    if ((int)blockIdx.x < packBlocks) {
        const int t = threadIdx.x;
        const int R0 = blockIdx.x * 64;

        if (t < 64) bs[t] = b[t];
#pragma unroll
        for (int k = 0; k < 4; ++k) {
            int f4 = k * 256 + t;
            int row = f4 >> 4;
            int c4 = (f4 & 15) * 4;
            int grow = min(R0 + row, Nsrc - 1);
            float4 v = reinterpret_cast<const float4*>(h)[(size_t)grow * 16 + (f4 & 15)];
            hT[row * 64 + c4 + 0] = bf16_rne_u(v.x);
            hT[row * 64 + c4 + 1] = bf16_rne_u(v.y);
            hT[row * 64 + c4 + 2] = bf16_rne_u(v.z);
            hT[row * 64 + c4 + 3] = bf16_rne_u(v.w);
            float4 w = reinterpret_cast<const float4*>(W)[f4];
            wT[row * 64 + c4 + 0] = bf16_rne_u(w.x);
            wT[row * 64 + c4 + 1] = bf16_rne_u(w.y);
            wT[row * 64 + c4 + 2] = bf16_rne_u(w.z);
            wT[row * 64 + c4 + 3] = bf16_rne_u(w.w);
        }
        __syncthreads();

        // MFMA 16x16x32 bf16; A[m=lane&15][k=quad*8+j]; C/D col=lane&15,row=quad*4+reg
        const int wave = t >> 6;
        const int lane = t & 63;
        const int m = lane & 15;
        const int quad = lane >> 4;

        bf16x8 afrag[2];
#pragma unroll
        for (int ks = 0; ks < 2; ++ks)
            afrag[ks] = *reinterpret_cast<const bf16x8*>(&hT[(wave * 16 + m) * 64 + ks * 32 + quad * 8]);

#pragma unroll
        for (int nt = 0; nt < 4; ++nt) {
            const int c0 = nt * 16;
            f32x4 acc = {0.f, 0.f, 0.f, 0.f};
#pragma unroll
            for (int ks = 0; ks < 2; ++ks) {
                bf16x8 bfrag = *reinterpret_cast<const bf16x8*>(&wT[(c0 + m) * 64 + ks * 32 + quad * 8]);
                acc = __builtin_amdgcn_mfma_f32_16x16x32_bf16(afrag[ks], bfrag, acc, 0, 0, 0);
            }
            const int col = c0 + m;
            const float bias = bs[col];
#pragma unroll
            for (int reg = 0; reg < 4; ++reg) {
                const int tr = wave * 16 + quad * 4 + reg;
                const int row = R0 + tr;
                if (row < Nsrc) {
                    float f = fmaxf(acc[reg] + bias, 0.f);
                    uint32_t val = (uint32_t)hT[tr * 64 + col] | ((uint32_t)bf16_rne_u(f) << 16);
                    __builtin_nontemporal_store(val, &packed[(size_t)row * D + col]);
                }
            }
        }
    } else {
        // ---- BIN role ----
        const int bid = (int)blockIdx.x - packBlocks;
        const int t = threadIdx.x;
        for (int k = t; k < NW; k += 256) wcount[k] = 0;
        __syncthreads();

        const int i = bid * 256 + t;
        const int e0 = i * EPT;
        const bool full = (e0 + EPT <= E);

        int4 d0, d1, d2, d3, s0, s1, s2, s3;
        if (full) {
            const int4* dp = reinterpret_cast<const int4*>(dst_idx) + i * 4;
            const int4* sp = reinterpret_cast<const int4*>(src_idx) + i * 4;
            d0 = dp[0]; d1 = dp[1]; d2 = dp[2]; d3 = dp[3];
            s0 = sp[0]; s1 = sp[1]; s2 = sp[2]; s3 = sp[3];
            atomicAdd(&wcount[d0.x >> WSHIFT], 1); atomicAdd(&wcount[d0.y >> WSHIFT], 1);
            atomicAdd(&wcount[d0.z >> WSHIFT], 1); atomicAdd(&wcount[d0.w >> WSHIFT], 1);
            atomicAdd(&wcount[d1.x >> WSHIFT], 1); atomicAdd(&wcount[d1.y >> WSHIFT], 1);
            atomicAdd(&wcount[d1.z >> WSHIFT], 1); atomicAdd(&wcount[d1.w >> WSHIFT], 1);
            atomicAdd(&wcount[d2.x >> WSHIFT], 1); atomicAdd(&wcount[d2.y >> WSHIFT], 1);
            atomicAdd(&wcount[d2.z >> WSHIFT], 1); atomicAdd(&wcount[d2.w >> WSHIFT], 1);
            atomicAdd(&wcount[d3.x >> WSHIFT], 1); atomicAdd(&wcount[d3.y >> WSHIFT], 1);
            atomicAdd(&wcount[d3.z >> WSHIFT], 1); atomicAdd(&wcount[d3.w >> WSHIFT], 1);
        } else {
            for (int e = e0; e < E; ++e) atomicAdd(&wcount[dst_idx[e] >> WSHIFT], 1);
        }
        __syncthreads();

        for (int k = t; k < NW; k += 256) {
            int c = wcount[k];
            wbase[k] = (c > 0) ? atomicAdd(&qcnt[k], c) : 0;
        }
        __syncthreads();

#define EMIT(dv, sv)                                                            \
        {                                                                       \
            int w_ = (dv) >> WSHIFT;                                            \
            int pos_ = atomicAdd(&wbase[w_], 1);                                \
            if (pos_ < QCAP)                                                    \
                queue[(size_t)w_ * QCAP + pos_] =                               \
                    (uint32_t)(sv) | ((uint32_t)((dv) & (WSZ - 1)) << 16);      \
        }
        if (full) {
            EMIT(d0.x, s0.x) EMIT(d0.y, s0.y) EMIT(d0.z, s0.z) EMIT(d0.w, s0.w)
            EMIT(d1.x, s1.x) EMIT(d1.y, s1.y) EMIT(d1.z, s1.z) EMIT(d1.w, s1.w)
            EMIT(d2.x, s2.x) EMIT(d2.y, s2.y) EMIT(d2.z, s2.z) EMIT(d2.w, s2.w)
            EMIT(d3.x, s3.x) EMIT(d3.y, s3.y) EMIT(d3.z, s3.z) EMIT(d3.w, s3.w)
        } else {
            for (int e = e0; e < E; ++e) { EMIT(dst_idx[e], src_idx[e]) }
        }
#undef EMIT
    }
}

// ---------------- per-dim accumulate: l += exp(x*y); a += exp(x*y)*f ----------------
__device__ inline void stepd(uint32_t u, float y, float& l, float& a) {
    float x = __uint_as_float(u << 16);           // low bf16 -> f32
    float f = __uint_as_float(u & 0xFFFF0000u);   // high bf16 -> f32
    float pe = __expf(x * y);                     // no max-sub: |x*y| <~ 30, safe in f32
    l += pe;
    a += pe * f;
}

__device__ inline void step4(uint4 u, const float4& y, float4& l, float4& a) {
    stepd(u.x, y.x, l.x, a.x);
    stepd(u.y, y.y, l.y, a.y);
    stepd(u.z, y.z, l.z, a.z);
    stepd(u.w, y.w, l.w, a.w);
}

// ================= fused sort + aggregate =================
// One block per 64-dst window: LDS counting sort of the window queue (replaces
// the separate sortwin kernel + its 10MB global round-trip), then R11's
// 16-lane-per-dst aggregation in 4 sequential batches, slot lists read from LDS.
__global__ __launch_bounds__(256) void gat_fused_kernel(const uint32_t* __restrict__ packed,
                                                        const float* __restrict__ h_dst,
                                                        const int* __restrict__ qcnt,
                                                        const uint32_t* __restrict__ queue,
                                                        float* __restrict__ out, int Ndst) {
    __shared__ uint32_t ent[QCAP];   // 8 KB
    __shared__ ushort srt[QCAP];     // 4 KB (src < 65536)
    __shared__ int hist[WSZ], sc[WSZ], cur[WSZ];
    const int w = blockIdx.x;
    const int t = threadIdx.x;
    const int n = min(qcnt[w], QCAP);

    for (int k = t; k < n; k += 256) ent[k] = queue[(size_t)w * QCAP + k];
    if (t < WSZ) hist[t] = 0;
    __syncthreads();
    for (int k = t; k < n; k += 256) atomicAdd(&hist[(ent[k] >> 16) & (WSZ - 1)], 1);
    __syncthreads();
    if (t < WSZ) sc[t] = hist[t];
    __syncthreads();
    for (int off = 1; off < WSZ; off <<= 1) {      // Hillis-Steele inclusive scan
        int v = (t >= off && t < WSZ) ? sc[t - off] : 0;
        __syncthreads();
        if (t < WSZ) sc[t] += v;
        __syncthreads();
    }
    if (t < WSZ) cur[t] = sc[t] - hist[t];         // exclusive
    __syncthreads();
    for (int k = t; k < n; k += 256) {
        uint32_t e = ent[k];
        int dl = (e >> 16) & (WSZ - 1);
        int pos = atomicAdd(&cur[dl], 1);          // LDS atomic
        srt[pos] = (ushort)(e & 0xFFFFu);
    }
    __syncthreads();

    // ---- aggregate: 4 batches x (16 groups of 16 lanes), R11 inner loop ----
    const int g = t >> 4;   // group 0..15
    const int q = t & 15;   // float4 slot within row
#pragma unroll
    for (int bt = 0; bt < 4; ++bt) {
        const int dl = bt * 16 + g;
        const int j = w * WSZ + dl;
        if (j >= Ndst) continue;

        const float4 y = reinterpret_cast<const float4*>(h_dst + (size_t)j * D)[q];
        const int nd = hist[dl];
        const int off = sc[dl] - hist[dl];

        float4 l0 = make_float4(0.f, 0.f, 0.f, 0.f), a0 = l0;
        float4 l1 = l0, a1 = l0, l2 = l0, a2 = l0, l3 = l0, a3 = l0;

        int p = 0;
        for (; p + 3 < nd; p += 4) {
            int s0 = srt[off + p], s1 = srt[off + p + 1];
            int s2 = srt[off + p + 2], s3 = srt[off + p + 3];
            uint4 u0 = reinterpret_cast<const uint4*>(packed + (size_t)s0 * D)[q];
            uint4 u1 = reinterpret_cast<const uint4*>(packed + (size_t)s1 * D)[q];
            uint4 u2 = reinterpret_cast<const uint4*>(packed + (size_t)s2 * D)[q];
            uint4 u3 = reinterpret_cast<const uint4*>(packed + (size_t)s3 * D)[q];
            step4(u0, y, l0, a0);
            step4(u1, y, l1, a1);
            step4(u2, y, l2, a2);
            step4(u3, y, l3, a3);
        }
        for (; p < nd; ++p) {
            int s0 = srt[off + p];
            uint4 u0 = reinterpret_cast<const uint4*>(packed + (size_t)s0 * D)[q];
            step4(u0, y, l0, a0);
        }

        l0.x += l1.x + l2.x + l3.x; a0.x += a1.x + a2.x + a3.x;
        l0.y += l1.y + l2.y + l3.y; a0.y += a1.y + a2.y + a3.y;
        l0.z += l1.z + l2.z + l3.z; a0.z += a1.z + a2.z + a3.z;
        l0.w += l1.w + l2.w + l3.w; a0.w += a1.w + a2.w + a3.w;

        float4 o;
        o.x = (l0.x > 0.f) ? a0.x / l0.x : 0.f;   // empty segment -> 0 (matches ref)
        o.y = (l0.y > 0.f) ? a0.y / l0.y : 0.f;
        o.z = (l0.z > 0.f) ? a0.z / l0.z : 0.f;
        o.w = (l0.w > 0.f) ? a0.w / l0.w : 0.f;
        reinterpret_cast<float4*>(out + (size_t)j * D)[q] = o;
    }
}

extern "C" void kernel_launch(void* const* d_in, const int* in_sizes, int n_in,
                              void* d_out, int out_size, void* d_ws, size_t ws_size,
                              hipStream_t stream) {
    const float* h_src = (const float*)d_in[0];
    const float* h_dst = (const float*)d_in[1];
    const int* src_idx = (const int*)d_in[2];
    const int* dst_idx = (const int*)d_in[3];
    const float* W_src = (const float*)d_in[4];
    const float* b_src = (const float*)d_in[5];
    float* out = (float*)d_out;

    const int Nsrc = in_sizes[0] / D;
    const int Ndst = in_sizes[1] / D;
    const int E = in_sizes[2];
    const int NW = (Ndst + WSZ - 1) >> WSHIFT;

    const int packBlocks = (Nsrc + 63) / 64;
    const int binBlocks = (E + 256 * EPT - 1) / (256 * EPT);   // read-once

    // workspace layout
    uint32_t* packed = (uint32_t*)d_ws;                    // Nsrc*D u32
    int*      qcnt   = (int*)(packed + (size_t)Nsrc * D);  // NWMAX
    uint32_t* queue  = (uint32_t*)(qcnt + NWMAX);          // NW*QCAP

    hipMemsetAsync(qcnt, 0, sizeof(int) * NWMAX, stream);

    prep_kernel<<<packBlocks + binBlocks, 256, 0, stream>>>(
        h_src, W_src, b_src, src_idx, dst_idx, packed, qcnt, queue,
        Nsrc, Ndst, E, packBlocks, NW);
    gat_fused_kernel<<<NW, 256, 0, stream>>>(packed, h_dst, qcnt, queue, out, Ndst);
}